// Round 14
// baseline (268.850 us; speedup 1.0000x reference)
//
#include <hip/hip_runtime.h>
#include <hip/hip_bf16.h>

#define TKN   2048
#define CDIM  256
#define PDIM  32
#define ODIM  32
#define HIDD  128
#define CCSZ  65536
#define TOTSZ 66560
#define KSPL  16

typedef unsigned short u16;
typedef __bf16 bf16x8 __attribute__((ext_vector_type(8)));
typedef float f32x4 __attribute__((ext_vector_type(4)));
typedef unsigned short u16x4 __attribute__((ext_vector_type(4)));
typedef unsigned short u16x8 __attribute__((ext_vector_type(8)));

__device__ __forceinline__ u16 f2b(float f){
  __hip_bfloat16 h = __float2bfloat16(f);
  return *reinterpret_cast<u16*>(&h);
}
__device__ __forceinline__ float gelu_exact(float x){
  return 0.5f * x * (1.0f + erff(x * 0.70710678118654752f));
}

// ---------------- prep: layernorm + h = q@w1.T + b1  -> H bf16 [2048][128]
__global__ __launch_bounds__(256) void k_prep_h(
    const float* __restrict__ query, const float* __restrict__ ln_w,
    const float* __restrict__ ln_b, const float* __restrict__ w1,
    const float* __restrict__ b1, u16* __restrict__ H){
  const int t = blockIdx.x;
  const int tid = threadIdx.x;
  __shared__ float qs[CDIM];
  __shared__ float red[8];
  __shared__ float stat[2];
  float v = query[(size_t)t*CDIM + tid];
  float s = v, s2 = v*v;
  #pragma unroll
  for(int o=32;o>0;o>>=1){ s += __shfl_down(s,o,64); s2 += __shfl_down(s2,o,64); }
  const int wv = tid>>6;
  if((tid&63)==0){ red[wv]=s; red[4+wv]=s2; }
  __syncthreads();
  if(tid==0){
    float ss=red[0]+red[1]+red[2]+red[3];
    float qq=red[4]+red[5]+red[6]+red[7];
    float mu=ss/(float)CDIM;
    float var=qq/(float)CDIM - mu*mu;
    stat[0]=mu; stat[1]=rsqrtf(var+1e-6f);
  }
  __syncthreads();
  qs[tid] = (v - stat[0])*stat[1]*ln_w[tid] + ln_b[tid];
  __syncthreads();
  if(tid < HIDD){
    const float* wr = w1 + (size_t)tid*CDIM;
    float acc = b1[tid];
    #pragma unroll 8
    for(int c=0;c<CDIM;c++) acc += qs[c]*wr[c];
    H[(size_t)t*HIDD + tid] = f2b(acc);
  }
}

// ---------------- prep: w2 -> bf16 in FRAGMENT-BLOCKED layout.
// n (fragment-order GEMM-N index): n<CCSZ: n = f*512+g*128+r*8+e <-> d=(f>>3)*16+r,
// c=(f&7)*32+g*8+e, w2 row j = c*256+d; n>=CCSZ: j=n.
// Storage: B-fragment for (panel q, ks, nt8) = one contiguous 1KB wave-load.
__global__ __launch_bounds__(256) void k_prep_w2(
    const float* __restrict__ w2, const float* __restrict__ b2,
    u16* __restrict__ w2s, float* __restrict__ b2p){
  const int gid = blockIdx.x*256 + threadIdx.x;   // 66560*16 threads
  const int n  = gid >> 4;
  const int ch = gid & 15;                        // k-chunk: k = ch*8 .. ch*8+7
  if(n >= TOTSZ) return;
  int j;
  if(n < CCSZ){
    const int f = n >> 9, rem = n & 511;
    const int g = rem >> 7, r = (rem >> 3) & 15, e = rem & 7;
    const int d = (f >> 3)*16 + r;
    const int c = (f & 7)*32 + g*8 + e;
    j = c*256 + d;
  } else {
    j = n;
  }
  const float* src = w2 + (size_t)j*HIDD + ch*8;
  u16x8 tv;
  #pragma unroll
  for(int i=0;i<8;i++) tv[i] = f2b(src[i]);
  const int q = n >> 7, ks = ch >> 2, nt8 = (n >> 4) & 7, kg = ch & 3, r15 = n & 15;
  *(u16x8*)(w2s + ((size_t)((q*4 + ks)*8 + nt8))*512 + (kg*16 + r15)*8) = tv;
  if(ch == 0) b2p[n] = b2[j];
}

// ---------------- prep: proj_w -> bf16
__global__ __launch_bounds__(256) void k_prep_pw(
    const float* __restrict__ pw, u16* __restrict__ pwb){
  const int gid = blockIdx.x*256 + threadIdx.x;   // 262144 threads
  const float* s = pw + (size_t)gid*8;
  u16x8 tv;
  #pragma unroll
  for(int i=0;i<8;i++) tv[i] = f2b(s[i]);
  *(u16x8*)(pwb + (size_t)gid*8) = tv;
}

// ---------------- params GEMM v9.1: r13 structure, S padded 136->132 (conflict-free
// transpose writes). grid (520, chnk/64), 256 threads = 4 waves; wave = 16 tok x 128 n.
__global__ __launch_bounds__(256, 6) void k_params(
    const u16* __restrict__ H, const u16* __restrict__ w2s,
    const float* __restrict__ b2p, u16* __restrict__ pbuf, int chnk){
  __shared__ __align__(16) u16 S[4][16][132];
  const int tid = threadIdx.x;
  const int lane = tid & 63;
  const int w = tid >> 6;
  const int q = blockIdx.x;
  const int n0 = q * 128;
  const int t0 = blockIdx.y*64 + w*16;      // wave's 16 tokens (chunk-local)
  const int r15 = lane & 15, g = lane >> 4;
  // A fragments: 16 token rows, K=128
  bf16x8 afr[4];
  {
    const u16* ap = H + (size_t)(t0 + r15)*HIDD + g*8;
    #pragma unroll
    for(int ks=0;ks<4;ks++) afr[ks] = *(const bf16x8*)(ap + ks*32);
  }
  float b2v[8];
  #pragma unroll
  for(int nt=0;nt<8;nt++) b2v[nt] = b2p[n0 + nt*16 + r15];
  f32x4 acc[8] = {};
  #pragma unroll
  for(int ks=0;ks<4;ks++){
    bf16x8 bfr[8];
    #pragma unroll
    for(int nt=0;nt<8;nt++)
      bfr[nt] = *(const bf16x8*)(w2s + ((size_t)((q*4 + ks)*8 + nt))*512 + lane*8);
    #pragma unroll
    for(int nt=0;nt<8;nt++)
      acc[nt] = __builtin_amdgcn_mfma_f32_16x16x32_bf16(afr[ks], bfr[nt], acc[nt], 0,0,0);
  }
  // per-wave transpose -> S[w][tok][n-within]; stride 132 u16 = conflict-free banks
  #pragma unroll
  for(int nt=0;nt<8;nt++)
    #pragma unroll
    for(int r=0;r<4;r++)
      S[w][g*4 + r][nt*16 + r15] = f2b(acc[nt][r] + b2v[nt]);
  // copy-out: 4 insts x 1KB contiguous (4 tokens x 256B per inst)
  u16* dst = pbuf + ((size_t)q*chnk + t0)*128;
  #pragma unroll
  for(int i=0;i<4;i++){
    const int lt = i*4 + (lane >> 4);
    const int jc = lane & 15;
    *(u16x8*)(dst + (size_t)lt*128 + jc*8) = *(const u16x8*)&S[w][lt][jc*8];
  }
}

// ---------------- per-token chain: 512 threads (8 waves), one block per token.
// pbuf panel layout: addr = (n>>7)*chnk*128 + t*128 + (n&127); af = 4x256B chunks.
__global__ __launch_bounds__(512, 4) void k_token(
    const float* __restrict__ xg, const u16* __restrict__ pbuf,
    const float* __restrict__ m_beta, const float* __restrict__ s_beta,
    u16* __restrict__ out2, int chnk){
  __shared__ u16 xs[PDIM][264];   // reused as out2 tile [ODIM][264] later
  __shared__ u16 smt[ODIM][40];
  __shared__ u16 o1[CDIM][40];
  const int tl = blockIdx.x;
  const int tid = threadIdx.x;
  const int lane = tid & 63;
  const int w = tid >> 6;                 // 0..7, owns d-range [w*32, w*32+32)
  const int r15 = lane & 15, g = lane >> 4;

  // preload ALL af fragments (independent of LDS; 16-deep pipeline)
  bf16x8 af[2][8];
  #pragma unroll
  for(int ks=0;ks<8;ks++)
    #pragma unroll
    for(int mt=0;mt<2;mt++){
      const int f = (w*2+mt)*8 + ks;
      af[mt][ks] = *(const bf16x8*)(pbuf + ((size_t)(4*f + g)*chnk + tl)*128 + r15*8);
    }

  // stage xs -> bf16 LDS [p][c]
  {
    const f32x4* src = (const f32x4*)(xg + (size_t)tl*8192);
    #pragma unroll
    for(int i=0;i<4;i++){
      const int idx = tid + 512*i;
      f32x4 v = src[idx];
      const int flat = idx*4;
      const int p = flat >> 8, c = flat & 255;
      u16x4 t4; t4[0]=f2b(v[0]); t4[1]=f2b(v[1]); t4[2]=f2b(v[2]); t4[3]=f2b(v[3]);
      *(u16x4*)&xs[p][c] = t4;
    }
  }
  // stage sm [o][p]: n = CCSZ + tid*8 -> panel 512 + (tid>>4), within (tid&15)*8
  if(tid < 128){
    const u16* s = pbuf + ((size_t)(512 + (tid>>4))*chnk + tl)*128 + (tid&15)*8;
    const int o = (tid*8) >> 5, p = (tid*8) & 31;
    *(u16x8*)&smt[o][p] = *(const u16x8*)s;
  }
  __syncthreads();

  // GEMM2: out1T[d][p] = sum_c cmT[d][c]*xs[p][c]
  f32x4 acc[2][2] = {};
  #pragma unroll
  for(int ks=0;ks<8;ks++){
    bf16x8 bf[2];
    #pragma unroll
    for(int nt=0;nt<2;nt++){
      const int p = nt*16 + r15;
      bf[nt] = *(const bf16x8*)&xs[p][ks*32 + g*8];
    }
    #pragma unroll
    for(int mt=0;mt<2;mt++)
      #pragma unroll
      for(int nt=0;nt<2;nt++)
        acc[mt][nt] = __builtin_amdgcn_mfma_f32_16x16x32_bf16(af[mt][ks], bf[nt], acc[mt][nt], 0,0,0);
  }
  // epilogue -> o1[d][p] (gelu(x + m_beta[d]))
  #pragma unroll
  for(int mt=0;mt<2;mt++){
    const int d0 = w*32 + mt*16 + g*4;
    const f32x4 mb = *(const f32x4*)&m_beta[d0];
    #pragma unroll
    for(int nt=0;nt<2;nt++){
      const int p = nt*16 + r15;
      #pragma unroll
      for(int r=0;r<4;r++)
        o1[d0+r][p] = f2b(gelu_exact(acc[mt][nt][r] + mb[r]));
    }
  }
  __syncthreads();

  // GEMM-sm: out2T[d][o] = sum_p o1[d][p]*sm[o][p]  (K=32, single step)
  f32x4 acc2[2][2] = {};
  {
    bf16x8 af2[2], bf2[2];
    #pragma unroll
    for(int mt=0;mt<2;mt++){
      const int d = w*32 + mt*16 + r15;
      af2[mt] = *(const bf16x8*)&o1[d][g*8];
    }
    #pragma unroll
    for(int nt=0;nt<2;nt++){
      const int o = nt*16 + r15;
      bf2[nt] = *(const bf16x8*)&smt[o][g*8];
    }
    #pragma unroll
    for(int mt=0;mt<2;mt++)
      #pragma unroll
      for(int nt=0;nt<2;nt++)
        acc2[mt][nt] = __builtin_amdgcn_mfma_f32_16x16x32_bf16(af2[mt], bf2[nt], acc2[mt][nt], 0,0,0);
  }
  // epilogue into xs buffer reused as out2 tile [o][d]
  u16 (*o2t)[264] = xs;
  #pragma unroll
  for(int nt=0;nt<2;nt++){
    const int o = nt*16 + r15;
    const float sb = s_beta[o];
    #pragma unroll
    for(int mt=0;mt<2;mt++){
      const int d0 = w*32 + mt*16 + g*4;
      u16x4 t4;
      #pragma unroll
      for(int r=0;r<4;r++) t4[r] = f2b(gelu_exact(acc2[mt][nt][r] + sb));
      *(u16x4*)&o2t[o][d0] = t4;
    }
  }
  __syncthreads();
  // copy out flat (k = o*256 + d)
  {
    u16* dst = out2 + (size_t)tl*8192;
    #pragma unroll
    for(int i=0;i<2;i++){
      const int flat = (i*512 + tid)*8;
      const int o = flat >> 8, dd = flat & 255;
      *(u16x8*)(dst + flat) = *(const u16x8*)&o2t[o][dd];
    }
  }
}

// ---------------- proj GEMM: 2-phase LDS-pipelined. part[kz][t][e] = sum_{k slice} out2[t][k]*pwb[e][k]
__global__ __launch_bounds__(512) void k_proj(
    const u16* __restrict__ out2, const u16* __restrict__ pwb,
    float* __restrict__ part){
  __shared__ u16 Ab[2][64*32];
  __shared__ u16 Bb[2][256*32];
  const int tid = threadIdx.x;
  const int lane = tid & 63, w = tid >> 6;
  const int r15 = lane & 15, g = lane >> 4;
  const int m0 = blockIdx.x * 64;
  const int k0 = blockIdx.y * 512;
  const int wm = (w >> 2) * 32;
  const int wn = (w & 3) * 64;
  const int srow = lane >> 2;
  const int cs   = lane & 3;
  const int a_row = (w & 3)*16 + srow;
  const u16* a_src = out2 + (size_t)(m0 + a_row)*8192 + k0 + (size_t)((cs ^ (a_row & 3))*8);
  const int b_row0 = (2*w)*16 + srow;
  const int b_row1 = (2*w+1)*16 + srow;
  const u16* b_src0 = pwb + (size_t)b_row0*8192 + k0 + (size_t)((cs ^ (b_row0 & 3))*8);
  const u16* b_src1 = pwb + (size_t)b_row1*8192 + k0 + (size_t)((cs ^ (b_row1 & 3))*8);

  f32x4 acc[2][4] = {};

  #define GL16(gp, lp) __builtin_amdgcn_global_load_lds( \
      (const __attribute__((address_space(1))) unsigned int*)(gp), \
      (__attribute__((address_space(3))) unsigned int*)(lp), 16, 0, 0)
  #define STAGE(buf, kt) do{                                         \
    const int ko = (kt)*32;                                          \
    if(w < 4) GL16(a_src + ko, (char*)&Ab[buf][0] + w*1024);         \
    GL16(b_src0 + ko, (char*)&Bb[buf][0] + (2*w)*1024);              \
    GL16(b_src1 + ko, (char*)&Bb[buf][0] + (2*w+1)*1024);            \
  }while(0)

  STAGE(0, 0);
  __syncthreads();
  int cur = 0;
  for(int kt=0; kt<16; kt++){
    if(kt < 15){ STAGE(cur^1, kt+1); }
    bf16x8 af[2], bf[4];
    #pragma unroll
    for(int mt=0;mt<2;mt++){
      const int row = wm + mt*16 + r15;
      af[mt] = *(const bf16x8*)((char*)&Ab[cur][0] + row*64 + ((g ^ (row&3))*16));
    }
    #pragma unroll
    for(int nt=0;nt<4;nt++){
      const int row = wn + nt*16 + r15;
      bf[nt] = *(const bf16x8*)((char*)&Bb[cur][0] + row*64 + ((g ^ (row&3))*16));
    }
    #pragma unroll
    for(int mt=0;mt<2;mt++)
      #pragma unroll
      for(int nt=0;nt<4;nt++)
        acc[mt][nt] = __builtin_amdgcn_mfma_f32_16x16x32_bf16(af[mt], bf[nt], acc[mt][nt], 0,0,0);
    __syncthreads();
    cur ^= 1;
  }
  #undef STAGE
  #undef GL16

  float* pbase = part + (size_t)blockIdx.y*TKN*CDIM;
  #pragma unroll
  for(int mt=0;mt<2;mt++)
    #pragma unroll
    for(int nt=0;nt<4;nt++){
      const int t = m0 + wm + mt*16 + g*4;
      const int e = wn + nt*16 + r15;
      #pragma unroll
      for(int r=0;r<4;r++)
        pbase[(size_t)(t+r)*CDIM + e] = acc[mt][nt][r];
    }
}

// ---------------- combine partials + proj_b (f32x4 vectorized; 512 blocks)
__global__ __launch_bounds__(256) void k_combine(
    const float* __restrict__ part, const float* __restrict__ pb,
    float* __restrict__ out){
  const int i4 = blockIdx.x*256 + threadIdx.x;   // 131072 f32x4's
  const int e4 = (i4 & 63)*4;
  f32x4 s = *(const f32x4*)&pb[e4];
  #pragma unroll
  for(int z=0;z<KSPL;z++) s += *(const f32x4*)&part[(size_t)z*524288 + (size_t)i4*4];
  *(f32x4*)&out[(size_t)i4*4] = s;
}

extern "C" void kernel_launch(void* const* d_in, const int* in_sizes, int n_in,
                              void* d_out, int out_size, void* d_ws, size_t ws_size,
                              hipStream_t stream){
  const float* x     = (const float*)d_in[0];
  const float* query = (const float*)d_in[1];
  const float* ln_w  = (const float*)d_in[2];
  const float* ln_b  = (const float*)d_in[3];
  const float* w1    = (const float*)d_in[4];
  const float* b1    = (const float*)d_in[5];
  const float* w2    = (const float*)d_in[6];
  const float* b2    = (const float*)d_in[7];
  const float* m_beta= (const float*)d_in[8];
  const float* s_beta= (const float*)d_in[9];
  const float* pw    = (const float*)d_in[10];
  const float* pb    = (const float*)d_in[11];
  float* out = (float*)d_out;
  char* ws = (char*)d_ws;

  // chnk=512: pbuf 68 MB -> retained in 256 MB L3 between k_params and k_token
  // (chnk=1024's 136 MB spilled; r13 showed pbuf round-trip hitting HBM at 2.4 TB/s).
  // Needs ~124 MB ws (measured ws = 256 MiB); fall back to 256 if smaller.
  const int chnk = (ws_size >= 130u*1024u*1024u) ? 512 : 256;
  const int nch  = TKN / chnk;

  size_t off = 0;
  u16* H     = (u16*)(ws + off);  off += (size_t)TKN*HIDD*2;
  u16* w2s   = (u16*)(ws + off);  off += (size_t)TOTSZ*HIDD*2;
  float* b2p = (float*)(ws + off);off += (size_t)TOTSZ*4;
  u16* pwb   = (u16*)(ws + off);  off += (size_t)CDIM*8192*2;
  u16* pbuf  = (u16*)(ws + off);  off += (size_t)chnk*TOTSZ*2;   // 520 panels x [chnk][128]
  u16* out2  = (u16*)(ws + off);  off += (size_t)TKN*8192*2;
  // part (16 x 2048 x 256 fp32 = 33.55 MB) aliases pbuf (>=34 MB, dead by k_proj).
  float* part= (float*)pbuf;

  k_prep_h<<<TKN, 256, 0, stream>>>(query, ln_w, ln_b, w1, b1, H);
  k_prep_w2<<<4160, 256, 0, stream>>>(w2, b2, w2s, b2p);
  k_prep_pw<<<1024, 256, 0, stream>>>(pw, pwb);
  for(int ch=0; ch<nch; ch++){
    k_params<<<dim3(520, chnk/64), 256, 0, stream>>>(H + (size_t)ch*chnk*HIDD, w2s, b2p, pbuf, chnk);
    k_token<<<chnk, 512, 0, stream>>>(x + (size_t)ch*chnk*8192, pbuf, m_beta, s_beta,
                                      out2 + (size_t)ch*chnk*8192, chnk);
  }
  k_proj<<<dim3(32,KSPL), 512, 0, stream>>>(out2, pwb, part);
  k_combine<<<512, 256, 0, stream>>>(part, pb, out);
}

// Round 15
// 253.621 us; speedup vs baseline: 1.0600x; 1.0600x over previous
//
#include <hip/hip_runtime.h>
#include <hip/hip_bf16.h>

#define TKN   2048
#define CDIM  256
#define PDIM  32
#define ODIM  32
#define HIDD  128
#define CCSZ  65536
#define TOTSZ 66560
#define KSPL  16

typedef unsigned short u16;
typedef __bf16 bf16x8 __attribute__((ext_vector_type(8)));
typedef float f32x4 __attribute__((ext_vector_type(4)));
typedef unsigned short u16x4 __attribute__((ext_vector_type(4)));
typedef unsigned short u16x8 __attribute__((ext_vector_type(8)));

__device__ __forceinline__ u16 f2b(float f){
  __hip_bfloat16 h = __float2bfloat16(f);
  return *reinterpret_cast<u16*>(&h);
}
__device__ __forceinline__ float gelu_exact(float x){
  return 0.5f * x * (1.0f + erff(x * 0.70710678118654752f));
}

// ---------------- prep: layernorm + h = q@w1.T + b1  -> H bf16 [2048][128]
__global__ __launch_bounds__(256) void k_prep_h(
    const float* __restrict__ query, const float* __restrict__ ln_w,
    const float* __restrict__ ln_b, const float* __restrict__ w1,
    const float* __restrict__ b1, u16* __restrict__ H){
  const int t = blockIdx.x;
  const int tid = threadIdx.x;
  __shared__ float qs[CDIM];
  __shared__ float red[8];
  __shared__ float stat[2];
  float v = query[(size_t)t*CDIM + tid];
  float s = v, s2 = v*v;
  #pragma unroll
  for(int o=32;o>0;o>>=1){ s += __shfl_down(s,o,64); s2 += __shfl_down(s2,o,64); }
  const int wv = tid>>6;
  if((tid&63)==0){ red[wv]=s; red[4+wv]=s2; }
  __syncthreads();
  if(tid==0){
    float ss=red[0]+red[1]+red[2]+red[3];
    float qq=red[4]+red[5]+red[6]+red[7];
    float mu=ss/(float)CDIM;
    float var=qq/(float)CDIM - mu*mu;
    stat[0]=mu; stat[1]=rsqrtf(var+1e-6f);
  }
  __syncthreads();
  qs[tid] = (v - stat[0])*stat[1]*ln_w[tid] + ln_b[tid];
  __syncthreads();
  if(tid < HIDD){
    const float* wr = w1 + (size_t)tid*CDIM;
    float acc = b1[tid];
    #pragma unroll 8
    for(int c=0;c<CDIM;c++) acc += qs[c]*wr[c];
    H[(size_t)t*HIDD + tid] = f2b(acc);
  }
}

// ---------------- prep: w2 -> bf16 in FRAGMENT-BLOCKED layout.
// n (fragment-order GEMM-N index): n<CCSZ: n = f*512+g*128+r*8+e <-> d=(f>>3)*16+r,
// c=(f&7)*32+g*8+e, w2 row j = c*256+d; n>=CCSZ: j=n.
// Storage: B-fragment for (panel q, ks, nt8) = one contiguous 1KB wave-load.
__global__ __launch_bounds__(256) void k_prep_w2(
    const float* __restrict__ w2, const float* __restrict__ b2,
    u16* __restrict__ w2s, float* __restrict__ b2p){
  const int gid = blockIdx.x*256 + threadIdx.x;   // 66560*16 threads
  const int n  = gid >> 4;
  const int ch = gid & 15;                        // k-chunk: k = ch*8 .. ch*8+7
  if(n >= TOTSZ) return;
  int j;
  if(n < CCSZ){
    const int f = n >> 9, rem = n & 511;
    const int g = rem >> 7, r = (rem >> 3) & 15, e = rem & 7;
    const int d = (f >> 3)*16 + r;
    const int c = (f & 7)*32 + g*8 + e;
    j = c*256 + d;
  } else {
    j = n;
  }
  const float* src = w2 + (size_t)j*HIDD + ch*8;
  u16x8 tv;
  #pragma unroll
  for(int i=0;i<8;i++) tv[i] = f2b(src[i]);
  const int q = n >> 7, ks = ch >> 2, nt8 = (n >> 4) & 7, kg = ch & 3, r15 = n & 15;
  *(u16x8*)(w2s + ((size_t)((q*4 + ks)*8 + nt8))*512 + (kg*16 + r15)*8) = tv;
  if(ch == 0) b2p[n] = b2[j];
}

// ---------------- prep: proj_w -> bf16
__global__ __launch_bounds__(256) void k_prep_pw(
    const float* __restrict__ pw, u16* __restrict__ pwb){
  const int gid = blockIdx.x*256 + threadIdx.x;   // 262144 threads
  const float* s = pw + (size_t)gid*8;
  u16x8 tv;
  #pragma unroll
  for(int i=0;i<8;i++) tv[i] = f2b(s[i]);
  *(u16x8*)(pwb + (size_t)gid*8) = tv;
}

// ---------------- params GEMM v10 (B-amortized m-loop AND high occupancy):
// grid (520, chnk/128), 256 threads = 4 waves: wni = n-half (64 n), wti = token-group.
// Wave = 16 tok x 64 n per m-step, m-loop 4 -> 64 tokens/wave. B-frags (bfr[4][4],
// 64 VGPR) loaded ONCE per wave as 1KB-contiguous reads -> B L2 traffic 1.06GB->266MB
// (r13's hidden L2 contention). VGPR ~115 -> launch_bounds(256,4) = 50% occ.
// Barrier-free; per-wave private LDS transpose; 128B-line panel stores (r9-verified).
__global__ __launch_bounds__(256, 4) void k_params(
    const u16* __restrict__ H, const u16* __restrict__ w2s,
    const float* __restrict__ b2p, u16* __restrict__ pbuf, int chnk){
  __shared__ __align__(16) u16 S[4][16][68];
  const int tid = threadIdx.x;
  const int lane = tid & 63;
  const int w = tid >> 6;
  const int q = blockIdx.x;
  const int wni = w & 1, wti = w >> 1;
  const int tg0 = blockIdx.y*128 + wti*64;   // wave's 64 tokens (chunk-local)
  const int r15 = lane & 15, g = lane >> 4;
  // B fragments ONCE: 4 ks x 4 nt for this wave's n-half; 1KB contiguous each
  bf16x8 bfr[4][4];
  #pragma unroll
  for(int ks=0;ks<4;ks++)
    #pragma unroll
    for(int nt=0;nt<4;nt++)
      bfr[ks][nt] = *(const bf16x8*)(w2s + ((size_t)((q*4 + ks)*8 + wni*4 + nt))*512 + lane*8);
  float b2v[4];
  #pragma unroll
  for(int nt=0;nt<4;nt++) b2v[nt] = b2p[q*128 + wni*64 + nt*16 + r15];
  const int ilt = lane >> 3, jc = lane & 7;
  for(int m=0; m<4; m++){
    const int t0 = tg0 + m*16;
    bf16x8 afr[4];
    {
      const u16* ap = H + (size_t)(t0 + r15)*HIDD + g*8;
      #pragma unroll
      for(int ks=0;ks<4;ks++) afr[ks] = *(const bf16x8*)(ap + ks*32);
    }
    f32x4 acc[4] = {};
    #pragma unroll
    for(int ks=0;ks<4;ks++)
      #pragma unroll
      for(int nt=0;nt<4;nt++)
        acc[nt] = __builtin_amdgcn_mfma_f32_16x16x32_bf16(afr[ks], bfr[ks][nt], acc[nt], 0,0,0);
    // per-wave transpose (in-order within wave -> no barrier); stride 68 u16: conflict-free
    #pragma unroll
    for(int nt=0;nt<4;nt++)
      #pragma unroll
      for(int r=0;r<4;r++)
        S[w][g*4 + r][nt*16 + r15] = f2b(acc[nt][r] + b2v[nt]);
    // copy-out: 2 insts x (8 tokens x 128B half-rows) — full 128B lines
    u16* dst = pbuf + ((size_t)q*chnk + t0)*128 + wni*64;
    #pragma unroll
    for(int i=0;i<2;i++){
      const int lt = i*8 + ilt;
      *(u16x8*)(dst + (size_t)lt*128 + jc*8) = *(const u16x8*)&S[w][lt][jc*8];
    }
  }
}

// ---------------- per-token chain: 512 threads (8 waves), one block per token.
// pbuf panel layout: addr = (n>>7)*chnk*128 + t*128 + (n&127); af = 4x256B chunks.
__global__ __launch_bounds__(512, 4) void k_token(
    const float* __restrict__ xg, const u16* __restrict__ pbuf,
    const float* __restrict__ m_beta, const float* __restrict__ s_beta,
    u16* __restrict__ out2, int chnk){
  __shared__ u16 xs[PDIM][264];   // reused as out2 tile [ODIM][264] later
  __shared__ u16 smt[ODIM][40];
  __shared__ u16 o1[CDIM][40];
  const int tl = blockIdx.x;
  const int tid = threadIdx.x;
  const int lane = tid & 63;
  const int w = tid >> 6;                 // 0..7, owns d-range [w*32, w*32+32)
  const int r15 = lane & 15, g = lane >> 4;

  // preload ALL af fragments (independent of LDS; 16-deep pipeline)
  bf16x8 af[2][8];
  #pragma unroll
  for(int ks=0;ks<8;ks++)
    #pragma unroll
    for(int mt=0;mt<2;mt++){
      const int f = (w*2+mt)*8 + ks;
      af[mt][ks] = *(const bf16x8*)(pbuf + ((size_t)(4*f + g)*chnk + tl)*128 + r15*8);
    }

  // stage xs -> bf16 LDS [p][c]
  {
    const f32x4* src = (const f32x4*)(xg + (size_t)tl*8192);
    #pragma unroll
    for(int i=0;i<4;i++){
      const int idx = tid + 512*i;
      f32x4 v = src[idx];
      const int flat = idx*4;
      const int p = flat >> 8, c = flat & 255;
      u16x4 t4; t4[0]=f2b(v[0]); t4[1]=f2b(v[1]); t4[2]=f2b(v[2]); t4[3]=f2b(v[3]);
      *(u16x4*)&xs[p][c] = t4;
    }
  }
  // stage sm [o][p]: n = CCSZ + tid*8 -> panel 512 + (tid>>4), within (tid&15)*8
  if(tid < 128){
    const u16* s = pbuf + ((size_t)(512 + (tid>>4))*chnk + tl)*128 + (tid&15)*8;
    const int o = (tid*8) >> 5, p = (tid*8) & 31;
    *(u16x8*)&smt[o][p] = *(const u16x8*)s;
  }
  __syncthreads();

  // GEMM2: out1T[d][p] = sum_c cmT[d][c]*xs[p][c]
  f32x4 acc[2][2] = {};
  #pragma unroll
  for(int ks=0;ks<8;ks++){
    bf16x8 bf[2];
    #pragma unroll
    for(int nt=0;nt<2;nt++){
      const int p = nt*16 + r15;
      bf[nt] = *(const bf16x8*)&xs[p][ks*32 + g*8];
    }
    #pragma unroll
    for(int mt=0;mt<2;mt++)
      #pragma unroll
      for(int nt=0;nt<2;nt++)
        acc[mt][nt] = __builtin_amdgcn_mfma_f32_16x16x32_bf16(af[mt][ks], bf[nt], acc[mt][nt], 0,0,0);
  }
  // epilogue -> o1[d][p] (gelu(x + m_beta[d]))
  #pragma unroll
  for(int mt=0;mt<2;mt++){
    const int d0 = w*32 + mt*16 + g*4;
    const f32x4 mb = *(const f32x4*)&m_beta[d0];
    #pragma unroll
    for(int nt=0;nt<2;nt++){
      const int p = nt*16 + r15;
      #pragma unroll
      for(int r=0;r<4;r++)
        o1[d0+r][p] = f2b(gelu_exact(acc[mt][nt][r] + mb[r]));
    }
  }
  __syncthreads();

  // GEMM-sm: out2T[d][o] = sum_p o1[d][p]*sm[o][p]  (K=32, single step)
  f32x4 acc2[2][2] = {};
  {
    bf16x8 af2[2], bf2[2];
    #pragma unroll
    for(int mt=0;mt<2;mt++){
      const int d = w*32 + mt*16 + r15;
      af2[mt] = *(const bf16x8*)&o1[d][g*8];
    }
    #pragma unroll
    for(int nt=0;nt<2;nt++){
      const int o = nt*16 + r15;
      bf2[nt] = *(const bf16x8*)&smt[o][g*8];
    }
    #pragma unroll
    for(int mt=0;mt<2;mt++)
      #pragma unroll
      for(int nt=0;nt<2;nt++)
        acc2[mt][nt] = __builtin_amdgcn_mfma_f32_16x16x32_bf16(af2[mt], bf2[nt], acc2[mt][nt], 0,0,0);
  }
  // epilogue into xs buffer reused as out2 tile [o][d]
  u16 (*o2t)[264] = xs;
  #pragma unroll
  for(int nt=0;nt<2;nt++){
    const int o = nt*16 + r15;
    const float sb = s_beta[o];
    #pragma unroll
    for(int mt=0;mt<2;mt++){
      const int d0 = w*32 + mt*16 + g*4;
      u16x4 t4;
      #pragma unroll
      for(int r=0;r<4;r++) t4[r] = f2b(gelu_exact(acc2[mt][nt][r] + sb));
      *(u16x4*)&o2t[o][d0] = t4;
    }
  }
  __syncthreads();
  // copy out flat (k = o*256 + d)
  {
    u16* dst = out2 + (size_t)tl*8192;
    #pragma unroll
    for(int i=0;i<2;i++){
      const int flat = (i*512 + tid)*8;
      const int o = flat >> 8, dd = flat & 255;
      *(u16x8*)(dst + flat) = *(const u16x8*)&o2t[o][dd];
    }
  }
}

// ---------------- proj GEMM: 2-phase LDS-pipelined. part[kz][t][e] = sum_{k slice} out2[t][k]*pwb[e][k]
__global__ __launch_bounds__(512) void k_proj(
    const u16* __restrict__ out2, const u16* __restrict__ pwb,
    float* __restrict__ part){
  __shared__ u16 Ab[2][64*32];
  __shared__ u16 Bb[2][256*32];
  const int tid = threadIdx.x;
  const int lane = tid & 63, w = tid >> 6;
  const int r15 = lane & 15, g = lane >> 4;
  const int m0 = blockIdx.x * 64;
  const int k0 = blockIdx.y * 512;
  const int wm = (w >> 2) * 32;
  const int wn = (w & 3) * 64;
  const int srow = lane >> 2;
  const int cs   = lane & 3;
  const int a_row = (w & 3)*16 + srow;
  const u16* a_src = out2 + (size_t)(m0 + a_row)*8192 + k0 + (size_t)((cs ^ (a_row & 3))*8);
  const int b_row0 = (2*w)*16 + srow;
  const int b_row1 = (2*w+1)*16 + srow;
  const u16* b_src0 = pwb + (size_t)b_row0*8192 + k0 + (size_t)((cs ^ (b_row0 & 3))*8);
  const u16* b_src1 = pwb + (size_t)b_row1*8192 + k0 + (size_t)((cs ^ (b_row1 & 3))*8);

  f32x4 acc[2][4] = {};

  #define GL16(gp, lp) __builtin_amdgcn_global_load_lds( \
      (const __attribute__((address_space(1))) unsigned int*)(gp), \
      (__attribute__((address_space(3))) unsigned int*)(lp), 16, 0, 0)
  #define STAGE(buf, kt) do{                                         \
    const int ko = (kt)*32;                                          \
    if(w < 4) GL16(a_src + ko, (char*)&Ab[buf][0] + w*1024);         \
    GL16(b_src0 + ko, (char*)&Bb[buf][0] + (2*w)*1024);              \
    GL16(b_src1 + ko, (char*)&Bb[buf][0] + (2*w+1)*1024);            \
  }while(0)

  STAGE(0, 0);
  __syncthreads();
  int cur = 0;
  for(int kt=0; kt<16; kt++){
    if(kt < 15){ STAGE(cur^1, kt+1); }
    bf16x8 af[2], bf[4];
    #pragma unroll
    for(int mt=0;mt<2;mt++){
      const int row = wm + mt*16 + r15;
      af[mt] = *(const bf16x8*)((char*)&Ab[cur][0] + row*64 + ((g ^ (row&3))*16));
    }
    #pragma unroll
    for(int nt=0;nt<4;nt++){
      const int row = wn + nt*16 + r15;
      bf[nt] = *(const bf16x8*)((char*)&Bb[cur][0] + row*64 + ((g ^ (row&3))*16));
    }
    #pragma unroll
    for(int mt=0;mt<2;mt++)
      #pragma unroll
      for(int nt=0;nt<4;nt++)
        acc[mt][nt] = __builtin_amdgcn_mfma_f32_16x16x32_bf16(af[mt], bf[nt], acc[mt][nt], 0,0,0);
    __syncthreads();
    cur ^= 1;
  }
  #undef STAGE
  #undef GL16

  float* pbase = part + (size_t)blockIdx.y*TKN*CDIM;
  #pragma unroll
  for(int mt=0;mt<2;mt++)
    #pragma unroll
    for(int nt=0;nt<4;nt++){
      const int t = m0 + wm + mt*16 + g*4;
      const int e = wn + nt*16 + r15;
      #pragma unroll
      for(int r=0;r<4;r++)
        pbase[(size_t)(t+r)*CDIM + e] = acc[mt][nt][r];
    }
}

// ---------------- combine partials + proj_b (f32x4 vectorized; 512 blocks)
__global__ __launch_bounds__(256) void k_combine(
    const float* __restrict__ part, const float* __restrict__ pb,
    float* __restrict__ out){
  const int i4 = blockIdx.x*256 + threadIdx.x;   // 131072 f32x4's
  const int e4 = (i4 & 63)*4;
  f32x4 s = *(const f32x4*)&pb[e4];
  #pragma unroll
  for(int z=0;z<KSPL;z++) s += *(const f32x4*)&part[(size_t)z*524288 + (size_t)i4*4];
  *(f32x4*)&out[(size_t)i4*4] = s;
}

extern "C" void kernel_launch(void* const* d_in, const int* in_sizes, int n_in,
                              void* d_out, int out_size, void* d_ws, size_t ws_size,
                              hipStream_t stream){
  const float* x     = (const float*)d_in[0];
  const float* query = (const float*)d_in[1];
  const float* ln_w  = (const float*)d_in[2];
  const float* ln_b  = (const float*)d_in[3];
  const float* w1    = (const float*)d_in[4];
  const float* b1    = (const float*)d_in[5];
  const float* w2    = (const float*)d_in[6];
  const float* b2    = (const float*)d_in[7];
  const float* m_beta= (const float*)d_in[8];
  const float* s_beta= (const float*)d_in[9];
  const float* pw    = (const float*)d_in[10];
  const float* pb    = (const float*)d_in[11];
  float* out = (float*)d_out;
  char* ws = (char*)d_ws;

  // chnk=1024 (r13 best; r14's 512 regressed from launch overhead). Needs ~192 MB.
  const size_t need_big = 192u*1024u*1024u;
  const int chnk = (ws_size >= need_big) ? 1024 : 256;
  const int nch  = TKN / chnk;

  size_t off = 0;
  u16* H     = (u16*)(ws + off);  off += (size_t)TKN*HIDD*2;
  u16* w2s   = (u16*)(ws + off);  off += (size_t)TOTSZ*HIDD*2;
  float* b2p = (float*)(ws + off);off += (size_t)TOTSZ*4;
  u16* pwb   = (u16*)(ws + off);  off += (size_t)CDIM*8192*2;
  u16* pbuf  = (u16*)(ws + off);  off += (size_t)chnk*TOTSZ*2;   // 520 panels x [chnk][128]
  u16* out2  = (u16*)(ws + off);  off += (size_t)TKN*8192*2;
  // part (16 x 2048 x 256 fp32 = 33.55 MB) aliases pbuf (>=34 MB, dead by k_proj).
  float* part= (float*)pbuf;

  k_prep_h<<<TKN, 256, 0, stream>>>(query, ln_w, ln_b, w1, b1, H);
  k_prep_w2<<<4160, 256, 0, stream>>>(w2, b2, w2s, b2p);
  k_prep_pw<<<1024, 256, 0, stream>>>(pw, pwb);
  for(int ch=0; ch<nch; ch++){
    k_params<<<dim3(520, chnk/128), 256, 0, stream>>>(H + (size_t)ch*chnk*HIDD, w2s, b2p, pbuf, chnk);
    k_token<<<chnk, 512, 0, stream>>>(x + (size_t)ch*chnk*8192, pbuf, m_beta, s_beta,
                                      out2 + (size_t)ch*chnk*8192, chnk);
  }
  k_proj<<<dim3(32,KSPL), 512, 0, stream>>>(out2, pwb, part);
  k_combine<<<512, 256, 0, stream>>>(part, pb, out);
}

// Round 16
// 228.161 us; speedup vs baseline: 1.1783x; 1.1116x over previous
//
#include <hip/hip_runtime.h>
#include <hip/hip_bf16.h>

#define TKN   2048
#define CDIM  256
#define PDIM  32
#define ODIM  32
#define HIDD  128
#define CCSZ  65536
#define TOTSZ 66560
#define KSPL  16

typedef unsigned short u16;
typedef __bf16 bf16x8 __attribute__((ext_vector_type(8)));
typedef float f32x4 __attribute__((ext_vector_type(4)));
typedef unsigned short u16x4 __attribute__((ext_vector_type(4)));
typedef unsigned short u16x8 __attribute__((ext_vector_type(8)));

__device__ __forceinline__ u16 f2b(float f){
  __hip_bfloat16 h = __float2bfloat16(f);
  return *reinterpret_cast<u16*>(&h);
}
__device__ __forceinline__ float gelu_exact(float x){
  return 0.5f * x * (1.0f + erff(x * 0.70710678118654752f));
}

// ---------------- prep: layernorm + h = q@w1.T + b1  -> H bf16 [2048][128]
__global__ __launch_bounds__(256) void k_prep_h(
    const float* __restrict__ query, const float* __restrict__ ln_w,
    const float* __restrict__ ln_b, const float* __restrict__ w1,
    const float* __restrict__ b1, u16* __restrict__ H){
  const int t = blockIdx.x;
  const int tid = threadIdx.x;
  __shared__ float qs[CDIM];
  __shared__ float red[8];
  __shared__ float stat[2];
  float v = query[(size_t)t*CDIM + tid];
  float s = v, s2 = v*v;
  #pragma unroll
  for(int o=32;o>0;o>>=1){ s += __shfl_down(s,o,64); s2 += __shfl_down(s2,o,64); }
  const int wv = tid>>6;
  if((tid&63)==0){ red[wv]=s; red[4+wv]=s2; }
  __syncthreads();
  if(tid==0){
    float ss=red[0]+red[1]+red[2]+red[3];
    float qq=red[4]+red[5]+red[6]+red[7];
    float mu=ss/(float)CDIM;
    float var=qq/(float)CDIM - mu*mu;
    stat[0]=mu; stat[1]=rsqrtf(var+1e-6f);
  }
  __syncthreads();
  qs[tid] = (v - stat[0])*stat[1]*ln_w[tid] + ln_b[tid];
  __syncthreads();
  if(tid < HIDD){
    const float* wr = w1 + (size_t)tid*CDIM;
    float acc = b1[tid];
    #pragma unroll 8
    for(int c=0;c<CDIM;c++) acc += qs[c]*wr[c];
    H[(size_t)t*HIDD + tid] = f2b(acc);
  }
}

// ---------------- prep: w2 -> bf16 in FRAGMENT-BLOCKED layout.
// n (fragment-order GEMM-N index): n<CCSZ: n = f*512+g*128+r*8+e <-> d=(f>>3)*16+r,
// c=(f&7)*32+g*8+e, w2 row j = c*256+d; n>=CCSZ: j=n.
// Storage: B-fragment for (panel q, ks, nt8) = one contiguous 1KB wave-load.
__global__ __launch_bounds__(256) void k_prep_w2(
    const float* __restrict__ w2, const float* __restrict__ b2,
    u16* __restrict__ w2s, float* __restrict__ b2p){
  const int gid = blockIdx.x*256 + threadIdx.x;   // 66560*16 threads
  const int n  = gid >> 4;
  const int ch = gid & 15;                        // k-chunk: k = ch*8 .. ch*8+7
  if(n >= TOTSZ) return;
  int j;
  if(n < CCSZ){
    const int f = n >> 9, rem = n & 511;
    const int g = rem >> 7, r = (rem >> 3) & 15, e = rem & 7;
    const int d = (f >> 3)*16 + r;
    const int c = (f & 7)*32 + g*8 + e;
    j = c*256 + d;
  } else {
    j = n;
  }
  const float* src = w2 + (size_t)j*HIDD + ch*8;
  u16x8 tv;
  #pragma unroll
  for(int i=0;i<8;i++) tv[i] = f2b(src[i]);
  const int q = n >> 7, ks = ch >> 2, nt8 = (n >> 4) & 7, kg = ch & 3, r15 = n & 15;
  *(u16x8*)(w2s + ((size_t)((q*4 + ks)*8 + nt8))*512 + (kg*16 + r15)*8) = tv;
  if(ch == 0) b2p[n] = b2[j];
}

// ---------------- prep: proj_w -> bf16
__global__ __launch_bounds__(256) void k_prep_pw(
    const float* __restrict__ pw, u16* __restrict__ pwb){
  const int gid = blockIdx.x*256 + threadIdx.x;   // 262144 threads
  const float* s = pw + (size_t)gid*8;
  u16x8 tv;
  #pragma unroll
  for(int i=0;i<8;i++) tv[i] = f2b(s[i]);
  *(u16x8*)(pwb + (size_t)gid*8) = tv;
}

// ---------------- params GEMM v9.2 = r13's v9 with B amortized over 2 m-steps.
// grid (520, chnk/128), 256 threads = 4 waves; wave = 16 tok x 128 n per m-step,
// 2 m-steps (128 tokens/block). ks-outer: bfr[8] loaded once per ks (1KB contiguous
// each) and used for BOTH m-steps -> B L2 traffic halved vs r13 (266->133 MB).
// Barrier-free; per-wave private LDS transpose; 16-lane x 256B full-row stores
// (r13-verified: WRITE_SIZE exact, no amplification).
__global__ __launch_bounds__(256, 3) void k_params(
    const u16* __restrict__ H, const u16* __restrict__ w2s,
    const float* __restrict__ b2p, u16* __restrict__ pbuf, int chnk){
  __shared__ __align__(16) u16 S[4][16][136];
  const int tid = threadIdx.x;
  const int lane = tid & 63;
  const int w = tid >> 6;
  const int q = blockIdx.x;
  const int n0 = q * 128;
  const int r15 = lane & 15, g = lane >> 4;
  const int tb = blockIdx.y*128 + w*16;     // wave's m=0 tokens (chunk-local)
  // A fragments for both m-steps (m*64 token offset)
  bf16x8 afr[2][4];
  #pragma unroll
  for(int m=0;m<2;m++){
    const u16* ap = H + (size_t)(tb + m*64 + r15)*HIDD + g*8;
    #pragma unroll
    for(int ks=0;ks<4;ks++) afr[m][ks] = *(const bf16x8*)(ap + ks*32);
  }
  float b2v[8];
  #pragma unroll
  for(int nt=0;nt<8;nt++) b2v[nt] = b2p[n0 + nt*16 + r15];
  f32x4 acc[2][8] = {};
  #pragma unroll
  for(int ks=0;ks<4;ks++){
    bf16x8 bfr[8];
    #pragma unroll
    for(int nt=0;nt<8;nt++)
      bfr[nt] = *(const bf16x8*)(w2s + ((size_t)((q*4 + ks)*8 + nt))*512 + lane*8);
    #pragma unroll
    for(int m=0;m<2;m++)
      #pragma unroll
      for(int nt=0;nt<8;nt++)
        acc[m][nt] = __builtin_amdgcn_mfma_f32_16x16x32_bf16(afr[m][ks], bfr[nt], acc[m][nt], 0,0,0);
  }
  #pragma unroll
  for(int m=0;m<2;m++){
    // per-wave transpose -> S[w][tok][n-within] (in-order within wave, no barrier)
    #pragma unroll
    for(int nt=0;nt<8;nt++)
      #pragma unroll
      for(int r=0;r<4;r++)
        S[w][g*4 + r][nt*16 + r15] = f2b(acc[m][nt][r] + b2v[nt]);
    // copy-out: 4 insts x 1KB contiguous (4 tokens x 256B full rows per inst)
    u16* dst = pbuf + ((size_t)q*chnk + tb + m*64)*128;
    #pragma unroll
    for(int i=0;i<4;i++){
      const int lt = i*4 + (lane >> 4);
      const int jc = lane & 15;
      *(u16x8*)(dst + (size_t)lt*128 + jc*8) = *(const u16x8*)&S[w][lt][jc*8];
    }
  }
}

// ---------------- per-token chain: 512 threads (8 waves), one block per token.
// pbuf panel layout: addr = (n>>7)*chnk*128 + t*128 + (n&127); af = 4x256B chunks.
__global__ __launch_bounds__(512, 4) void k_token(
    const float* __restrict__ xg, const u16* __restrict__ pbuf,
    const float* __restrict__ m_beta, const float* __restrict__ s_beta,
    u16* __restrict__ out2, int chnk){
  __shared__ u16 xs[PDIM][264];   // reused as out2 tile [ODIM][264] later
  __shared__ u16 smt[ODIM][40];
  __shared__ u16 o1[CDIM][40];
  const int tl = blockIdx.x;
  const int tid = threadIdx.x;
  const int lane = tid & 63;
  const int w = tid >> 6;                 // 0..7, owns d-range [w*32, w*32+32)
  const int r15 = lane & 15, g = lane >> 4;

  // preload ALL af fragments (independent of LDS; 16-deep pipeline)
  bf16x8 af[2][8];
  #pragma unroll
  for(int ks=0;ks<8;ks++)
    #pragma unroll
    for(int mt=0;mt<2;mt++){
      const int f = (w*2+mt)*8 + ks;
      af[mt][ks] = *(const bf16x8*)(pbuf + ((size_t)(4*f + g)*chnk + tl)*128 + r15*8);
    }

  // stage xs -> bf16 LDS [p][c]
  {
    const f32x4* src = (const f32x4*)(xg + (size_t)tl*8192);
    #pragma unroll
    for(int i=0;i<4;i++){
      const int idx = tid + 512*i;
      f32x4 v = src[idx];
      const int flat = idx*4;
      const int p = flat >> 8, c = flat & 255;
      u16x4 t4; t4[0]=f2b(v[0]); t4[1]=f2b(v[1]); t4[2]=f2b(v[2]); t4[3]=f2b(v[3]);
      *(u16x4*)&xs[p][c] = t4;
    }
  }
  // stage sm [o][p]: n = CCSZ + tid*8 -> panel 512 + (tid>>4), within (tid&15)*8
  if(tid < 128){
    const u16* s = pbuf + ((size_t)(512 + (tid>>4))*chnk + tl)*128 + (tid&15)*8;
    const int o = (tid*8) >> 5, p = (tid*8) & 31;
    *(u16x8*)&smt[o][p] = *(const u16x8*)s;
  }
  __syncthreads();

  // GEMM2: out1T[d][p] = sum_c cmT[d][c]*xs[p][c]
  f32x4 acc[2][2] = {};
  #pragma unroll
  for(int ks=0;ks<8;ks++){
    bf16x8 bf[2];
    #pragma unroll
    for(int nt=0;nt<2;nt++){
      const int p = nt*16 + r15;
      bf[nt] = *(const bf16x8*)&xs[p][ks*32 + g*8];
    }
    #pragma unroll
    for(int mt=0;mt<2;mt++)
      #pragma unroll
      for(int nt=0;nt<2;nt++)
        acc[mt][nt] = __builtin_amdgcn_mfma_f32_16x16x32_bf16(af[mt][ks], bf[nt], acc[mt][nt], 0,0,0);
  }
  // epilogue -> o1[d][p] (gelu(x + m_beta[d]))
  #pragma unroll
  for(int mt=0;mt<2;mt++){
    const int d0 = w*32 + mt*16 + g*4;
    const f32x4 mb = *(const f32x4*)&m_beta[d0];
    #pragma unroll
    for(int nt=0;nt<2;nt++){
      const int p = nt*16 + r15;
      #pragma unroll
      for(int r=0;r<4;r++)
        o1[d0+r][p] = f2b(gelu_exact(acc[mt][nt][r] + mb[r]));
    }
  }
  __syncthreads();

  // GEMM-sm: out2T[d][o] = sum_p o1[d][p]*sm[o][p]  (K=32, single step)
  f32x4 acc2[2][2] = {};
  {
    bf16x8 af2[2], bf2[2];
    #pragma unroll
    for(int mt=0;mt<2;mt++){
      const int d = w*32 + mt*16 + r15;
      af2[mt] = *(const bf16x8*)&o1[d][g*8];
    }
    #pragma unroll
    for(int nt=0;nt<2;nt++){
      const int o = nt*16 + r15;
      bf2[nt] = *(const bf16x8*)&smt[o][g*8];
    }
    #pragma unroll
    for(int mt=0;mt<2;mt++)
      #pragma unroll
      for(int nt=0;nt<2;nt++)
        acc2[mt][nt] = __builtin_amdgcn_mfma_f32_16x16x32_bf16(af2[mt], bf2[nt], acc2[mt][nt], 0,0,0);
  }
  // epilogue into xs buffer reused as out2 tile [o][d]
  u16 (*o2t)[264] = xs;
  #pragma unroll
  for(int nt=0;nt<2;nt++){
    const int o = nt*16 + r15;
    const float sb = s_beta[o];
    #pragma unroll
    for(int mt=0;mt<2;mt++){
      const int d0 = w*32 + mt*16 + g*4;
      u16x4 t4;
      #pragma unroll
      for(int r=0;r<4;r++) t4[r] = f2b(gelu_exact(acc2[mt][nt][r] + sb));
      *(u16x4*)&o2t[o][d0] = t4;
    }
  }
  __syncthreads();
  // copy out flat (k = o*256 + d)
  {
    u16* dst = out2 + (size_t)tl*8192;
    #pragma unroll
    for(int i=0;i<2;i++){
      const int flat = (i*512 + tid)*8;
      const int o = flat >> 8, dd = flat & 255;
      *(u16x8*)(dst + flat) = *(const u16x8*)&o2t[o][dd];
    }
  }
}

// ---------------- proj GEMM: 2-phase LDS-pipelined. part[kz][t][e] = sum_{k slice} out2[t][k]*pwb[e][k]
__global__ __launch_bounds__(512) void k_proj(
    const u16* __restrict__ out2, const u16* __restrict__ pwb,
    float* __restrict__ part){
  __shared__ u16 Ab[2][64*32];
  __shared__ u16 Bb[2][256*32];
  const int tid = threadIdx.x;
  const int lane = tid & 63, w = tid >> 6;
  const int r15 = lane & 15, g = lane >> 4;
  const int m0 = blockIdx.x * 64;
  const int k0 = blockIdx.y * 512;
  const int wm = (w >> 2) * 32;
  const int wn = (w & 3) * 64;
  const int srow = lane >> 2;
  const int cs   = lane & 3;
  const int a_row = (w & 3)*16 + srow;
  const u16* a_src = out2 + (size_t)(m0 + a_row)*8192 + k0 + (size_t)((cs ^ (a_row & 3))*8);
  const int b_row0 = (2*w)*16 + srow;
  const int b_row1 = (2*w+1)*16 + srow;
  const u16* b_src0 = pwb + (size_t)b_row0*8192 + k0 + (size_t)((cs ^ (b_row0 & 3))*8);
  const u16* b_src1 = pwb + (size_t)b_row1*8192 + k0 + (size_t)((cs ^ (b_row1 & 3))*8);

  f32x4 acc[2][4] = {};

  #define GL16(gp, lp) __builtin_amdgcn_global_load_lds( \
      (const __attribute__((address_space(1))) unsigned int*)(gp), \
      (__attribute__((address_space(3))) unsigned int*)(lp), 16, 0, 0)
  #define STAGE(buf, kt) do{                                         \
    const int ko = (kt)*32;                                          \
    if(w < 4) GL16(a_src + ko, (char*)&Ab[buf][0] + w*1024);         \
    GL16(b_src0 + ko, (char*)&Bb[buf][0] + (2*w)*1024);              \
    GL16(b_src1 + ko, (char*)&Bb[buf][0] + (2*w+1)*1024);            \
  }while(0)

  STAGE(0, 0);
  __syncthreads();
  int cur = 0;
  for(int kt=0; kt<16; kt++){
    if(kt < 15){ STAGE(cur^1, kt+1); }
    bf16x8 af[2], bf[4];
    #pragma unroll
    for(int mt=0;mt<2;mt++){
      const int row = wm + mt*16 + r15;
      af[mt] = *(const bf16x8*)((char*)&Ab[cur][0] + row*64 + ((g ^ (row&3))*16));
    }
    #pragma unroll
    for(int nt=0;nt<4;nt++){
      const int row = wn + nt*16 + r15;
      bf[nt] = *(const bf16x8*)((char*)&Bb[cur][0] + row*64 + ((g ^ (row&3))*16));
    }
    #pragma unroll
    for(int mt=0;mt<2;mt++)
      #pragma unroll
      for(int nt=0;nt<4;nt++)
        acc[mt][nt] = __builtin_amdgcn_mfma_f32_16x16x32_bf16(af[mt], bf[nt], acc[mt][nt], 0,0,0);
    __syncthreads();
    cur ^= 1;
  }
  #undef STAGE
  #undef GL16

  float* pbase = part + (size_t)blockIdx.y*TKN*CDIM;
  #pragma unroll
  for(int mt=0;mt<2;mt++)
    #pragma unroll
    for(int nt=0;nt<4;nt++){
      const int t = m0 + wm + mt*16 + g*4;
      const int e = wn + nt*16 + r15;
      #pragma unroll
      for(int r=0;r<4;r++)
        pbase[(size_t)(t+r)*CDIM + e] = acc[mt][nt][r];
    }
}

// ---------------- combine partials + proj_b (f32x4 vectorized; 512 blocks)
__global__ __launch_bounds__(256) void k_combine(
    const float* __restrict__ part, const float* __restrict__ pb,
    float* __restrict__ out){
  const int i4 = blockIdx.x*256 + threadIdx.x;   // 131072 f32x4's
  const int e4 = (i4 & 63)*4;
  f32x4 s = *(const f32x4*)&pb[e4];
  #pragma unroll
  for(int z=0;z<KSPL;z++) s += *(const f32x4*)&part[(size_t)z*524288 + (size_t)i4*4];
  *(f32x4*)&out[(size_t)i4*4] = s;
}

extern "C" void kernel_launch(void* const* d_in, const int* in_sizes, int n_in,
                              void* d_out, int out_size, void* d_ws, size_t ws_size,
                              hipStream_t stream){
  const float* x     = (const float*)d_in[0];
  const float* query = (const float*)d_in[1];
  const float* ln_w  = (const float*)d_in[2];
  const float* ln_b  = (const float*)d_in[3];
  const float* w1    = (const float*)d_in[4];
  const float* b1    = (const float*)d_in[5];
  const float* w2    = (const float*)d_in[6];
  const float* b2    = (const float*)d_in[7];
  const float* m_beta= (const float*)d_in[8];
  const float* s_beta= (const float*)d_in[9];
  const float* pw    = (const float*)d_in[10];
  const float* pb    = (const float*)d_in[11];
  float* out = (float*)d_out;
  char* ws = (char*)d_ws;

  // chnk=1024 (r13 best). Needs ~192 MB (measured ws = 256 MiB).
  const size_t need_big = 192u*1024u*1024u;
  const int chnk = (ws_size >= need_big) ? 1024 : 256;
  const int nch  = TKN / chnk;

  size_t off = 0;
  u16* H     = (u16*)(ws + off);  off += (size_t)TKN*HIDD*2;
  u16* w2s   = (u16*)(ws + off);  off += (size_t)TOTSZ*HIDD*2;
  float* b2p = (float*)(ws + off);off += (size_t)TOTSZ*4;
  u16* pwb   = (u16*)(ws + off);  off += (size_t)CDIM*8192*2;
  u16* pbuf  = (u16*)(ws + off);  off += (size_t)chnk*TOTSZ*2;   // 520 panels x [chnk][128]
  u16* out2  = (u16*)(ws + off);  off += (size_t)TKN*8192*2;
  // part (16 x 2048 x 256 fp32 = 33.55 MB) aliases pbuf (>=34 MB, dead by k_proj).
  float* part= (float*)pbuf;

  k_prep_h<<<TKN, 256, 0, stream>>>(query, ln_w, ln_b, w1, b1, H);
  k_prep_w2<<<4160, 256, 0, stream>>>(w2, b2, w2s, b2p);
  k_prep_pw<<<1024, 256, 0, stream>>>(pw, pwb);
  for(int ch=0; ch<nch; ch++){
    k_params<<<dim3(520, chnk/128), 256, 0, stream>>>(H + (size_t)ch*chnk*HIDD, w2s, b2p, pbuf, chnk);
    k_token<<<chnk, 512, 0, stream>>>(x + (size_t)ch*chnk*8192, pbuf, m_beta, s_beta,
                                      out2 + (size_t)ch*chnk*8192, chnk);
  }
  k_proj<<<dim3(32,KSPL), 512, 0, stream>>>(out2, pwb, part);
  k_combine<<<512, 256, 0, stream>>>(part, pb, out);
}